// Round 4
// baseline (322.511 us; speedup 1.0000x reference)
//
#include <hip/hip_runtime.h>
#include <stdint.h>

// ---------------------------------------------------------------------------
// NT-Xent loss, B=8192, D=128, T=0.5, N=16384.
// loss = mean_i( -sim[i,pair(i)] + logsumexp_j sim[i,j] ), diag masked.
//   Sum_i pos_i = 4 * sum(z1 .* z2)                  (exact fp32)
//   lse_i via bf16 MFMA Gram + FIXED-SHIFT exp-sum:
//     zb = bf16(z * sqrt(2*log2e))  =>  mfma y = sim_nat * log2(e)
//     acc initialized to -128  =>  mfma output is y - 128 directly
//     s_i = sum_j exp2(y_ij - 128);  lse_i = ln2 * (128 + log2(s_i))
//   exp2 via RAW v_exp_f32: args < -126 flush to 0 == correct here.
// Pipeline: TRIPLE-buffered global_load_lds, ONE barrier per tile, counted
// vmcnt(2) so prefetch (issued right after the barrier) spans whole tiles.
// 8-wave blocks, grid 512 = exactly 2 blocks/CU (96KB LDS, 16 waves/CU).
// ---------------------------------------------------------------------------

typedef __attribute__((ext_vector_type(8))) short s16x8;     // 8 bf16 (4 VGPR)
typedef __attribute__((ext_vector_type(16))) float f32x16;   // 32x32 mfma acc

#define N_TOT   16384
#define NHALF   8192
#define DDIM    128
#define NQ      16               // column splits
#define QW      (N_TOT / NQ)     // 1024 cols per block
#define BN      64               // cols per LDS tile
#define NT      (QW / BN)        // 16 tiles
#define BM      512              // rows per block (8 waves x 64 rows)
#define NRB     (N_TOT / BM)     // 32 row blocks
#define CSH     128.0f           // fixed exponent shift (log2 units)
#define LN2     0.69314718055994530942f
#define BF_SCALE 1.6986436f      // sqrt(2*log2(e))

__device__ __forceinline__ unsigned short f2bf(float f) {
    union { float f; unsigned int u; } v; v.f = f;
    unsigned int u = v.u;
    unsigned int r = (u + 0x7FFFu + ((u >> 16) & 1u)) >> 16;  // RNE
    return (unsigned short)r;
}

__device__ __forceinline__ void gload_lds16(const void* g, void* l) {
    __builtin_amdgcn_global_load_lds(
        (const __attribute__((address_space(1))) void*)g,
        (__attribute__((address_space(3))) void*)l, 16, 0, 0);
}

// --- fused cast(+scale) + positives partials + ws accumulator zeroing -------
__global__ __launch_bounds__(256) void k_castpos(const float* __restrict__ z1,
                                                 const float* __restrict__ z2,
                                                 unsigned short* __restrict__ zb,
                                                 float* __restrict__ pos_part,
                                                 float* __restrict__ ws_acc) {
    __shared__ float red[4];
    int i = blockIdx.x * 256 + threadIdx.x;      // 0..262143
    if (i == 0) { ws_acc[0] = 0.f; ((unsigned int*)ws_acc)[1] = 0u; }
    float4 a = ((const float4*)z1)[i];
    float4 b = ((const float4*)z2)[i];
    ushort4 oa, ob;
    oa.x = f2bf(a.x * BF_SCALE); oa.y = f2bf(a.y * BF_SCALE);
    oa.z = f2bf(a.z * BF_SCALE); oa.w = f2bf(a.w * BF_SCALE);
    ob.x = f2bf(b.x * BF_SCALE); ob.y = f2bf(b.y * BF_SCALE);
    ob.z = f2bf(b.z * BF_SCALE); ob.w = f2bf(b.w * BF_SCALE);
    ((ushort4*)zb)[i] = oa;
    ((ushort4*)(zb + (size_t)NHALF * DDIM))[i] = ob;
    float s = a.x * b.x + a.y * b.y + a.z * b.z + a.w * b.w;
    for (int o = 32; o; o >>= 1) s += __shfl_xor(s, o);
    int lane = threadIdx.x & 63, w = threadIdx.x >> 6;
    if (lane == 0) red[w] = s;
    __syncthreads();
    if (threadIdx.x == 0) pos_part[blockIdx.x] = red[0] + red[1] + red[2] + red[3];
}

// --- main: fused Gram + fixed-shift exp row-sum -----------------------------
__global__ __launch_bounds__(512, 4) void k_main(const unsigned short* __restrict__ zb,
                                                 float* __restrict__ ps) {
    __shared__ s16x8 tile[3][BN * 16];   // 3 x 16KB

    const int tid  = threadIdx.x;
    const int lane = tid & 63;
    const int w    = tid >> 6;           // 0..7
    const int h    = lane >> 5;
    const int l31  = lane & 31;

    const int bid = blockIdx.x;
    const int q   = bid >> 5;            // 0..NQ-1
    const int rb  = bid & 31;            // row block
    const int rowB     = rb * BM + w * 64;
    const int colStart = q * QW;

    // row fragments for two 32-row sets (mfma B operand)
    s16x8 rf0[8], rf1[8];
    {
        const s16x8* rp0 = (const s16x8*)(zb + (size_t)(rowB + l31) * DDIM);
        const s16x8* rp1 = (const s16x8*)(zb + (size_t)(rowB + 32 + l31) * DDIM);
        #pragma unroll
        for (int ks = 0; ks < 8; ++ks) { rf0[ks] = rp0[ks * 2 + h]; rf1[ks] = rp1[ks * 2 + h]; }
    }

    // staging: 16 wave-issues/tile across 8 waves (2 per wave). Issue e,
    // lane l writes linear LDS chunk e*64+l; inverse-swizzled global source
    // col=e*4+(l>>4), chunk=(l&15)^(col&15) -> LDS holds swizzled layout.
    int soff[2];
    #pragma unroll
    for (int j = 0; j < 2; ++j) {
        int e = w * 2 + j;
        int col = e * 4 + (lane >> 4);
        int chunk = (lane & 15) ^ (col & 15);
        soff[j] = col * 256 + chunk * 16;          // bytes within tile span
    }

    // prologue: issue tiles 0 and 1 (4 outstanding loads per wave)
    #pragma unroll
    for (int j = 0; j < 2; ++j)
        gload_lds16((const char*)zb + (size_t)colStart * 256 + soff[j],
                    (char*)(&tile[0][0]) + (w * 2 + j) * 1024);
    #pragma unroll
    for (int j = 0; j < 2; ++j)
        gload_lds16((const char*)zb + (size_t)(colStart + BN) * 256 + soff[j],
                    (char*)(&tile[1][0]) + (w * 2 + j) * 1024);

    float sa[4] = {0.f, 0.f, 0.f, 0.f};
    float sb[4] = {0.f, 0.f, 0.f, 0.f};

    int bc = 0;                          // buffer holding tile t
    int bp = 2;                          // buffer to prefetch into (t+2)
    for (int t = 0; t < NT; ++t) {
        // gate: tile t's 2 loads done; tile t+1's 2 stay in flight
        if (t < NT - 1) asm volatile("s_waitcnt vmcnt(2)" ::: "memory");
        else            asm volatile("s_waitcnt vmcnt(0)" ::: "memory");
        __builtin_amdgcn_s_barrier();    // all waves: t visible, t-1 compute done
        // refill freed buffer with tile t+2 — flies across the whole tile
        if (t + 2 < NT) {
            #pragma unroll
            for (int j = 0; j < 2; ++j)
                gload_lds16((const char*)zb + (size_t)(colStart + (t + 2) * BN) * 256 + soff[j],
                            (char*)(&tile[0][0]) + bp * 16384 + (w * 2 + j) * 1024);
        }
        const int colBase = colStart + t * BN;
        const s16x8* tbase = &tile[0][0] + bc * (BN * 16);
        #pragma unroll
        for (int sdx = 0; sdx < 2; ++sdx) {
            const int c  = sdx * 32 + l31;
            const int cx = c & 15;
            const s16x8* tb = tbase + c * 16;
            s16x8 a[8];
            #pragma unroll
            for (int ks = 0; ks < 8; ++ks) a[ks] = tb[(ks * 2 + h) ^ cx];
            f32x16 acc0 = {-CSH, -CSH, -CSH, -CSH, -CSH, -CSH, -CSH, -CSH,
                           -CSH, -CSH, -CSH, -CSH, -CSH, -CSH, -CSH, -CSH};
            f32x16 acc1 = acc0;
            #pragma unroll
            for (int ks = 0; ks < 8; ++ks) {
                acc0 = __builtin_amdgcn_mfma_f32_32x32x16_bf16(a[ks], rf0[ks], acc0, 0, 0, 0);
                acc1 = __builtin_amdgcn_mfma_f32_32x32x16_bf16(a[ks], rf1[ks], acc1, 0, 0, 0);
            }
            const int cb = colBase + sdx * 32;
            if (cb == rowB) {           // diagonal hits row-set 0 (wave-uniform)
                #pragma unroll
                for (int r2 = 0; r2 < 16; ++r2) {
                    int crow = (r2 & 3) + 8 * (r2 >> 2) + 4 * h;
                    if (crow == l31) acc0[r2] = -1e30f;
                }
            }
            if (cb == rowB + 32) {      // diagonal hits row-set 1
                #pragma unroll
                for (int r2 = 0; r2 < 16; ++r2) {
                    int crow = (r2 & 3) + 8 * (r2 >> 2) + 4 * h;
                    if (crow == l31) acc1[r2] = -1e30f;
                }
            }
            #pragma unroll
            for (int r2 = 0; r2 < 16; r2 += 4) {
                sa[0] += __builtin_amdgcn_exp2f(acc0[r2 + 0]);
                sa[1] += __builtin_amdgcn_exp2f(acc0[r2 + 1]);
                sa[2] += __builtin_amdgcn_exp2f(acc0[r2 + 2]);
                sa[3] += __builtin_amdgcn_exp2f(acc0[r2 + 3]);
                sb[0] += __builtin_amdgcn_exp2f(acc1[r2 + 0]);
                sb[1] += __builtin_amdgcn_exp2f(acc1[r2 + 1]);
                sb[2] += __builtin_amdgcn_exp2f(acc1[r2 + 2]);
                sb[3] += __builtin_amdgcn_exp2f(acc1[r2 + 3]);
            }
        }
        bc = (bc == 2) ? 0 : bc + 1;
        bp = (bp == 2) ? 0 : bp + 1;
    }

    // merge the two col-half lanes (l, l+32) of each row; write partials
    float sA = (sa[0] + sa[1]) + (sa[2] + sa[3]);
    float sB = (sb[0] + sb[1]) + (sb[2] + sb[3]);
    sA += __shfl_xor(sA, 32);
    sB += __shfl_xor(sB, 32);
    if (lane < 32) {
        ps[(size_t)q * N_TOT + rowB + l31]      = sA;
        ps[(size_t)q * N_TOT + rowB + 32 + l31] = sB;
    }
}

// --- combine NQ partials -> lse, grid-reduce, last block writes out ---------
__global__ __launch_bounds__(256) void k_cf(const float* __restrict__ ps,
                                            const float* __restrict__ pos_part,
                                            float* __restrict__ ws_acc,
                                            float* __restrict__ out) {
    __shared__ float red[4];
    __shared__ int last;
    const int tid = threadIdx.x;
    const int base = blockIdx.x * 1024;
    float ls = 0.f;
    #pragma unroll
    for (int k = 0; k < 4; ++k) {
        int row = base + k * 256 + tid;
        float s = 0.f;
        #pragma unroll
        for (int qq = 0; qq < NQ; ++qq) s += ps[(size_t)qq * N_TOT + row];
        ls += LN2 * (CSH + log2f(s));
    }
    for (int o = 32; o; o >>= 1) ls += __shfl_xor(ls, o);
    int lane = tid & 63, wv = tid >> 6;
    if (lane == 0) red[wv] = ls;
    __syncthreads();
    if (tid == 0) {
        atomicAdd(&ws_acc[0], red[0] + red[1] + red[2] + red[3]);
        __threadfence();
        unsigned int old = atomicAdd(&((unsigned int*)ws_acc)[1], 1u);
        last = (old == 15u) ? 1 : 0;
    }
    __syncthreads();
    if (last) {
        float p = pos_part[tid] + pos_part[tid + 256] +
                  pos_part[tid + 512] + pos_part[tid + 768];
        for (int o = 32; o; o >>= 1) p += __shfl_xor(p, o);
        if (lane == 0) red[wv] = p;
        __syncthreads();
        if (tid == 0) {
            float lse_tot = atomicAdd(&ws_acc[0], 0.f);   // coherent read
            float pos_tot = red[0] + red[1] + red[2] + red[3];
            out[0] = (lse_tot - 4.0f * pos_tot) * (1.0f / (float)N_TOT);
        }
    }
}

extern "C" void kernel_launch(void* const* d_in, const int* in_sizes, int n_in,
                              void* d_out, int out_size, void* d_ws, size_t ws_size,
                              hipStream_t stream) {
    const float* z1 = (const float*)d_in[0];
    const float* z2 = (const float*)d_in[1];
    float* out = (float*)d_out;

    char* ws = (char*)d_ws;
    float* ps       = (float*)ws;                          // NQ*N floats = 1 MB
    float* ws_acc   = (float*)(ws + (1u << 20));           // [lse_acc, ctr]
    float* pos_part = (float*)(ws + (1u << 20) + 1024);    // 1024 floats
    unsigned short* zb = (unsigned short*)(ws + (2u << 20)); // 4 MB bf16

    k_castpos<<<dim3(1024), dim3(256), 0, stream>>>(z1, z2, zb, pos_part, ws_acc);
    k_main<<<dim3(NRB * NQ), dim3(512), 0, stream>>>(zb, ps);
    k_cf<<<dim3(16), dim3(256), 0, stream>>>(ps, pos_part, ws_acc, out);
}

// Round 5
// 138.628 us; speedup vs baseline: 2.3265x; 2.3265x over previous
//
#include <hip/hip_runtime.h>
#include <stdint.h>

// ---------------------------------------------------------------------------
// NT-Xent loss, B=8192, D=128, T=0.5, N=16384.
// loss = mean_i( -sim[i,pair(i)] + logsumexp_j sim[i,j] ), diag masked.
//   Sum_i pos_i = 4 * sum(z1 .* z2)                  (exact fp32)
//   lse_i via bf16 MFMA Gram + FIXED-SHIFT exp-sum:
//     zb = bf16(z * sqrt(2*log2e))  =>  mfma y = sim_nat * log2(e)
//     acc initialized to -128  =>  mfma output is y - 128 directly
//     s_i = sum_j exp2(y_ij - 128);  lse_i = ln2 * (128 + log2(s_i))
//   exp2 via RAW v_exp_f32: args < -126 flush to 0 == correct here.
// Structure: 256-thr blocks (4 waves x 64 rows), TRIPLE-buffered LDS tiles,
// ONE barrier per tile, refill issued right after the barrier (depth-2
// prefetch, counted vmcnt(4)). Grid 64 row-blocks x 12 col-splits = 768
// = exactly 3 blocks/CU (48KB LDS each) -> no serial tail phase.
// NOTE: plain __launch_bounds__(256) — round-4's (512,4) min-waves caused
// a 64-VGPR allocation + rf spill to scratch (848MB FETCH). Do not re-add.
// ---------------------------------------------------------------------------

typedef __attribute__((ext_vector_type(8))) short s16x8;     // 8 bf16 (4 VGPR)
typedef __attribute__((ext_vector_type(16))) float f32x16;   // 32x32 mfma acc

#define N_TOT   16384
#define NHALF   8192
#define DDIM    128
#define NQ      12               // column splits (grid 64*12=768 = 3/CU)
#define TT      256              // total 64-col tiles over N
#define BN      64               // cols per LDS tile
#define BM      256              // rows per block (4 waves x 64 rows)
#define NRB     (N_TOT / BM)     // 64 row blocks
#define CSH     128.0f           // fixed exponent shift (log2 units)
#define LN2     0.69314718055994530942f
#define BF_SCALE 1.6986436f      // sqrt(2*log2(e))

__device__ __forceinline__ unsigned short f2bf(float f) {
    union { float f; unsigned int u; } v; v.f = f;
    unsigned int u = v.u;
    unsigned int r = (u + 0x7FFFu + ((u >> 16) & 1u)) >> 16;  // RNE
    return (unsigned short)r;
}

__device__ __forceinline__ void gload_lds16(const void* g, void* l) {
    __builtin_amdgcn_global_load_lds(
        (const __attribute__((address_space(1))) void*)g,
        (__attribute__((address_space(3))) void*)l, 16, 0, 0);
}

// --- fused cast(+scale) + positives partials + ws accumulator zeroing -------
__global__ __launch_bounds__(256) void k_castpos(const float* __restrict__ z1,
                                                 const float* __restrict__ z2,
                                                 unsigned short* __restrict__ zb,
                                                 float* __restrict__ pos_part,
                                                 float* __restrict__ ws_acc) {
    __shared__ float red[4];
    int i = blockIdx.x * 256 + threadIdx.x;      // 0..262143
    if (i == 0) { ws_acc[0] = 0.f; ((unsigned int*)ws_acc)[1] = 0u; }
    float4 a = ((const float4*)z1)[i];
    float4 b = ((const float4*)z2)[i];
    ushort4 oa, ob;
    oa.x = f2bf(a.x * BF_SCALE); oa.y = f2bf(a.y * BF_SCALE);
    oa.z = f2bf(a.z * BF_SCALE); oa.w = f2bf(a.w * BF_SCALE);
    ob.x = f2bf(b.x * BF_SCALE); ob.y = f2bf(b.y * BF_SCALE);
    ob.z = f2bf(b.z * BF_SCALE); ob.w = f2bf(b.w * BF_SCALE);
    ((ushort4*)zb)[i] = oa;
    ((ushort4*)(zb + (size_t)NHALF * DDIM))[i] = ob;
    float s = a.x * b.x + a.y * b.y + a.z * b.z + a.w * b.w;
    for (int o = 32; o; o >>= 1) s += __shfl_xor(s, o);
    int lane = threadIdx.x & 63, w = threadIdx.x >> 6;
    if (lane == 0) red[w] = s;
    __syncthreads();
    if (threadIdx.x == 0) pos_part[blockIdx.x] = red[0] + red[1] + red[2] + red[3];
}

// --- main: fused Gram + fixed-shift exp row-sum -----------------------------
__global__ __launch_bounds__(256) void k_main(const unsigned short* __restrict__ zb,
                                              float* __restrict__ ps) {
    __shared__ s16x8 tile[3][BN * 16];   // 3 x 16KB

    const int tid  = threadIdx.x;
    const int lane = tid & 63;
    const int w    = tid >> 6;           // 0..3
    const int h    = lane >> 5;
    const int l31  = lane & 31;

    const int bid = blockIdx.x;
    const int q   = bid >> 6;            // 0..NQ-1
    const int rb  = bid & 63;            // row block
    const int rowB   = rb * BM + w * 64;
    // this q's tile range: [(q*TT)/NQ, ((q+1)*TT)/NQ) -> 21 or 22 tiles
    const int tstart = (q * TT) / NQ;
    const int ntile  = ((q + 1) * TT) / NQ - tstart;

    // row fragments for two 32-row sets (mfma B operand)
    s16x8 rf0[8], rf1[8];
    {
        const s16x8* rp0 = (const s16x8*)(zb + (size_t)(rowB + l31) * DDIM);
        const s16x8* rp1 = (const s16x8*)(zb + (size_t)(rowB + 32 + l31) * DDIM);
        #pragma unroll
        for (int ks = 0; ks < 8; ++ks) { rf0[ks] = rp0[ks * 2 + h]; rf1[ks] = rp1[ks * 2 + h]; }
    }

    // staging: 16 wave-issues/tile (4 per wave). Issue e, lane l writes linear
    // LDS chunk e*64+l; inverse-swizzled global source col=e*4+(l>>4),
    // chunk=(l&15)^(col&15)  ==> LDS holds swizzled layout.
    int soff[4];
    #pragma unroll
    for (int j = 0; j < 4; ++j) {
        int e = w * 4 + j;
        int col = e * 4 + (lane >> 4);
        int chunk = (lane & 15) ^ (col & 15);
        soff[j] = col * 256 + chunk * 16;          // bytes within tile span
    }

    // prologue: issue tiles 0 and 1 (8 outstanding loads per wave)
    #pragma unroll
    for (int j = 0; j < 4; ++j)
        gload_lds16((const char*)zb + (size_t)tstart * 16384 + soff[j],
                    (char*)(&tile[0][0]) + (w * 4 + j) * 1024);
    #pragma unroll
    for (int j = 0; j < 4; ++j)
        gload_lds16((const char*)zb + (size_t)(tstart + 1) * 16384 + soff[j],
                    (char*)(&tile[1][0]) + (w * 4 + j) * 1024);

    float sa[4] = {0.f, 0.f, 0.f, 0.f};
    float sb[4] = {0.f, 0.f, 0.f, 0.f};

    int bc = 0;                          // buffer holding tile t
    int bp = 2;                          // buffer to prefetch into (t+2)
    for (int t = 0; t < ntile; ++t) {
        // gate: tile t's 4 loads done; tile t+1's 4 stay in flight
        if (t < ntile - 1) asm volatile("s_waitcnt vmcnt(4)" ::: "memory");
        else               asm volatile("s_waitcnt vmcnt(0)" ::: "memory");
        __builtin_amdgcn_s_barrier();    // t visible; compute of t-1 done by all
        // refill freed buffer with tile t+2 — flies across the whole tile t
        if (t + 2 < ntile) {
            #pragma unroll
            for (int j = 0; j < 4; ++j)
                gload_lds16((const char*)zb + (size_t)(tstart + t + 2) * 16384 + soff[j],
                            (char*)(&tile[0][0]) + bp * 16384 + (w * 4 + j) * 1024);
        }
        const int colBase = (tstart + t) * BN;
        const s16x8* tbase = &tile[0][0] + bc * (BN * 16);
        #pragma unroll
        for (int sdx = 0; sdx < 2; ++sdx) {
            const int c  = sdx * 32 + l31;
            const int cx = c & 15;
            const s16x8* tb = tbase + c * 16;
            s16x8 a[8];
            #pragma unroll
            for (int ks = 0; ks < 8; ++ks) a[ks] = tb[(ks * 2 + h) ^ cx];
            f32x16 acc0 = {-CSH, -CSH, -CSH, -CSH, -CSH, -CSH, -CSH, -CSH,
                           -CSH, -CSH, -CSH, -CSH, -CSH, -CSH, -CSH, -CSH};
            f32x16 acc1 = acc0;
            __builtin_amdgcn_s_setprio(1);
            #pragma unroll
            for (int ks = 0; ks < 8; ++ks) {
                acc0 = __builtin_amdgcn_mfma_f32_32x32x16_bf16(a[ks], rf0[ks], acc0, 0, 0, 0);
                acc1 = __builtin_amdgcn_mfma_f32_32x32x16_bf16(a[ks], rf1[ks], acc1, 0, 0, 0);
            }
            __builtin_amdgcn_s_setprio(0);
            const int cb = colBase + sdx * 32;
            if (cb == rowB) {           // diagonal hits row-set 0 (wave-uniform)
                #pragma unroll
                for (int r2 = 0; r2 < 16; ++r2) {
                    int crow = (r2 & 3) + 8 * (r2 >> 2) + 4 * h;
                    if (crow == l31) acc0[r2] = -1e30f;
                }
            }
            if (cb == rowB + 32) {      // diagonal hits row-set 1
                #pragma unroll
                for (int r2 = 0; r2 < 16; ++r2) {
                    int crow = (r2 & 3) + 8 * (r2 >> 2) + 4 * h;
                    if (crow == l31) acc1[r2] = -1e30f;
                }
            }
            #pragma unroll
            for (int r2 = 0; r2 < 16; r2 += 4) {
                sa[0] += __builtin_amdgcn_exp2f(acc0[r2 + 0]);
                sa[1] += __builtin_amdgcn_exp2f(acc0[r2 + 1]);
                sa[2] += __builtin_amdgcn_exp2f(acc0[r2 + 2]);
                sa[3] += __builtin_amdgcn_exp2f(acc0[r2 + 3]);
                sb[0] += __builtin_amdgcn_exp2f(acc1[r2 + 0]);
                sb[1] += __builtin_amdgcn_exp2f(acc1[r2 + 1]);
                sb[2] += __builtin_amdgcn_exp2f(acc1[r2 + 2]);
                sb[3] += __builtin_amdgcn_exp2f(acc1[r2 + 3]);
            }
        }
        bc = (bc == 2) ? 0 : bc + 1;
        bp = (bp == 2) ? 0 : bp + 1;
    }

    // merge the two col-half lanes (l, l+32) of each row; write partials
    float sA = (sa[0] + sa[1]) + (sa[2] + sa[3]);
    float sB = (sb[0] + sb[1]) + (sb[2] + sb[3]);
    sA += __shfl_xor(sA, 32);
    sB += __shfl_xor(sB, 32);
    if (lane < 32) {
        ps[(size_t)q * N_TOT + rowB + l31]      = sA;
        ps[(size_t)q * N_TOT + rowB + 32 + l31] = sB;
    }
}

// --- combine NQ partials -> lse, grid-reduce, last block writes out ---------
__global__ __launch_bounds__(256) void k_cf(const float* __restrict__ ps,
                                            const float* __restrict__ pos_part,
                                            float* __restrict__ ws_acc,
                                            float* __restrict__ out) {
    __shared__ float red[4];
    __shared__ int last;
    const int tid = threadIdx.x;
    const int base = blockIdx.x * 1024;
    float ls = 0.f;
    #pragma unroll
    for (int k = 0; k < 4; ++k) {
        int row = base + k * 256 + tid;
        float s = 0.f;
        #pragma unroll
        for (int qq = 0; qq < NQ; ++qq) s += ps[(size_t)qq * N_TOT + row];
        ls += LN2 * (CSH + log2f(s));
    }
    for (int o = 32; o; o >>= 1) ls += __shfl_xor(ls, o);
    int lane = tid & 63, wv = tid >> 6;
    if (lane == 0) red[wv] = ls;
    __syncthreads();
    if (tid == 0) {
        atomicAdd(&ws_acc[0], red[0] + red[1] + red[2] + red[3]);
        __threadfence();
        unsigned int old = atomicAdd(&((unsigned int*)ws_acc)[1], 1u);
        last = (old == 15u) ? 1 : 0;
    }
    __syncthreads();
    if (last) {
        float p = pos_part[tid] + pos_part[tid + 256] +
                  pos_part[tid + 512] + pos_part[tid + 768];
        for (int o = 32; o; o >>= 1) p += __shfl_xor(p, o);
        if (lane == 0) red[wv] = p;
        __syncthreads();
        if (tid == 0) {
            float lse_tot = atomicAdd(&ws_acc[0], 0.f);   // coherent read
            float pos_tot = red[0] + red[1] + red[2] + red[3];
            out[0] = (lse_tot - 4.0f * pos_tot) * (1.0f / (float)N_TOT);
        }
    }
}

extern "C" void kernel_launch(void* const* d_in, const int* in_sizes, int n_in,
                              void* d_out, int out_size, void* d_ws, size_t ws_size,
                              hipStream_t stream) {
    const float* z1 = (const float*)d_in[0];
    const float* z2 = (const float*)d_in[1];
    float* out = (float*)d_out;

    char* ws = (char*)d_ws;
    float* ps       = (float*)ws;                          // NQ*N floats (768KB)
    float* ws_acc   = (float*)(ws + (1u << 20));           // [lse_acc, ctr]
    float* pos_part = (float*)(ws + (1u << 20) + 1024);    // 1024 floats
    unsigned short* zb = (unsigned short*)(ws + (2u << 20)); // 4 MB bf16

    k_castpos<<<dim3(1024), dim3(256), 0, stream>>>(z1, z2, zb, pos_part, ws_acc);
    k_main<<<dim3(NRB * NQ), dim3(256), 0, stream>>>(zb, ps);
    k_cf<<<dim3(16), dim3(256), 0, stream>>>(ps, pos_part, ws_acc, out);
}